// Round 17
// baseline (122.922 us; speedup 1.0000x reference)
//
#include <hip/hip_runtime.h>

namespace {

constexpr int GV   = 48;
constexpr int NV   = 8;
constexpr int NH   = 27;
constexpr int NW   = 27;
constexpr int L    = NH * NW;     // 729
constexpr int C    = 1152;
constexpr int CD   = 288;
constexpr int NPTS = NV * L;      // 5832
constexpr int NVOX = GV * GV * GV;// 110592
constexpr int MAXP = 16;          // max recorded points per voxel

typedef __attribute__((ext_vector_type(8))) short short8;
typedef __attribute__((ext_vector_type(4))) float f32x4;

__device__ __forceinline__ unsigned short f2bf(float x) {
    unsigned u = __float_as_uint(x);
    unsigned r = u + 0x7fffu + ((u >> 16) & 1u);   // round-to-nearest-even
    return (unsigned short)(r >> 16);
}
__device__ __forceinline__ float bf2f(unsigned short h) {
    return __uint_as_float(((unsigned)h) << 16);
}

// ---- combo: weight transposes + cnt_i zero + w3 j-major transpose ----------
constexpr int NB_T   = (C / 32) * (CD / 32);          // 324 per matrix
constexpr int NB_ZC  = (NVOX / 4 + 255) / 256;        // 108 (int4/thread)
constexpr int NB_W3  = 8;                             // 7776 floats / 972
constexpr int B_ZC   = 2 * NB_T;                      // 648
constexpr int B_W3   = B_ZC + NB_ZC;                  // 756
constexpr int NB_ALL = B_W3 + NB_W3;                  // 764

__global__ __launch_bounds__(256) void k_combo(const float* __restrict__ w_down,
                                               const float* __restrict__ w_up,
                                               const float* __restrict__ w3,
                                               unsigned short* __restrict__ wdt,
                                               unsigned short* __restrict__ wut,
                                               float* __restrict__ w3t,
                                               int* __restrict__ cnt_i) {
    const int b   = blockIdx.x;
    const int tid = threadIdx.x;
    if (b < B_ZC) {
        __shared__ float t[32][33];
        const float* W; unsigned short* Wt; int K, N, kb, nb;
        if (b < NB_T) {
            W = w_down; Wt = wdt; K = C; N = CD;
            kb = (b % (C / 32)) * 32; nb = (b / (C / 32)) * 32;
        } else {
            int bb = b - NB_T;
            W = w_up; Wt = wut; K = CD; N = C;
            nb = (bb % (C / 32)) * 32; kb = (bb / (C / 32)) * 32;
        }
#pragma unroll
        for (int i = 0; i < 4; ++i) {
            int r = (tid >> 5) + i * 8, c = tid & 31;
            t[r][c] = W[(size_t)(kb + r) * N + nb + c];
        }
        __syncthreads();
#pragma unroll
        for (int i = 0; i < 4; ++i) {
            int r = (tid >> 5) + i * 8, c = tid & 31;
            Wt[(size_t)(nb + r) * K + kb + c] = f2bf(t[c][r]);
        }
    } else if (b < B_W3) {
        int i = (b - B_ZC) * 256 + tid;
        if (i < NVOX / 4)
            reinterpret_cast<int4*>(cnt_i)[i] = make_int4(0, 0, 0, 0);
    } else {
        int base = (b - B_W3) * 972;
        for (int k = tid; k < 972; k += 256) {
            int d = base + k;              // d < 7776
            int j = d / 288, ch = d % 288;
            w3t[d] = w3[ch * 27 + j];
        }
    }
}

__device__ __forceinline__ float gelu_tanh(float a) {
    float a3 = a * a * a;
    float inner = 0.7978845608028654f * (a + 0.044715f * a3);
    return 0.5f * a * (1.0f + tanhf(inner));
}

// Depthwise 3x3x3 conv at gathered voxels, vectorized: 7 points/block,
// 36 lanes/point, short8 x-loads, float4 w3t loads, per-point entry lists.
constexpr int C3_PTS = 7;
__global__ __launch_bounds__(256) void k_conv3(const int* __restrict__ coords,
                                               const unsigned short* __restrict__ x,
                                               const int* __restrict__ cnt_i,
                                               const int* __restrict__ vox_pts,
                                               const float* __restrict__ w3t,
                                               unsigned short* __restrict__ ptf) {
    __shared__ int   ent_pj[C3_PTS][27 * MAXP];
    __shared__ float ent_r[C3_PTS][27 * MAXP];
    __shared__ int   nent[C3_PTS];
    const int tid = threadIdx.x;
    const int p0  = blockIdx.x * C3_PTS;
    if (tid < C3_PTS) nent[tid] = 0;
    __syncthreads();
    if (tid < C3_PTS * 27) {
        int pp = tid / 27, j = tid - pp * 27;
        int p  = p0 + pp;
        if (p < NPTS) {
            int dz = j / 9, rem = j - dz * 9, dy = rem / 3, dx = rem - dy * 3;
            int c0 = coords[p * 3 + 0], c1 = coords[p * 3 + 1], c2 = coords[p * 3 + 2];
            int z = c0 + dz - 1, y = c1 + dy - 1, x2 = c2 + dx - 1;
            if ((unsigned)z < (unsigned)GV && (unsigned)y < (unsigned)GV &&
                (unsigned)x2 < (unsigned)GV) {
                int n = (z * GV + y) * GV + x2;
                int c = cnt_i[n];
                if (c > 0) {
                    int cc = c < MAXP ? c : MAXP;
                    float r = 1.0f / (float)c;
                    int base = atomicAdd(&nent[pp], cc);
                    for (int q = 0; q < cc; ++q) {
                        ent_pj[pp][base + q] = (vox_pts[n * MAXP + q] << 5) | j;
                        ent_r[pp][base + q]  = r;
                    }
                }
            }
        }
    }
    __syncthreads();
    const int pp = tid / 36, s = tid % 36;
    const int p  = p0 + pp;
    if (pp >= C3_PTS || p >= NPTS) return;
    const int ne = nent[pp];
    float acc[8] = {0.f, 0.f, 0.f, 0.f, 0.f, 0.f, 0.f, 0.f};
    for (int i = 0; i < ne; ++i) {
        int e  = ent_pj[pp][i];
        int p2 = e >> 5, j = e & 31;
        float r = ent_r[pp][i];
        short8 d = *reinterpret_cast<const short8*>(x + (size_t)p2 * CD + s * 8);
        const float4* wp = reinterpret_cast<const float4*>(w3t + j * 288 + s * 8);
        float4 w0 = wp[0], w1 = wp[1];
        acc[0] += w0.x * r * bf2f((unsigned short)d[0]);
        acc[1] += w0.y * r * bf2f((unsigned short)d[1]);
        acc[2] += w0.z * r * bf2f((unsigned short)d[2]);
        acc[3] += w0.w * r * bf2f((unsigned short)d[3]);
        acc[4] += w1.x * r * bf2f((unsigned short)d[4]);
        acc[5] += w1.y * r * bf2f((unsigned short)d[5]);
        acc[6] += w1.z * r * bf2f((unsigned short)d[6]);
        acc[7] += w1.w * r * bf2f((unsigned short)d[7]);
    }
    short8 h;
#pragma unroll
    for (int c = 0; c < 8; ++c) h[c] = (short)f2bf(gelu_tanh(acc[c]));
    *reinterpret_cast<short8*>(ptf + (size_t)p * CD + s * 8) = h;
}

// LDS swizzles: [rows][32] and [rows][64] bf16 tiles, slot = 16B unit.
__device__ __forceinline__ int swz(int row, int slot) {
    return row * 32 + ((slot ^ ((row >> 1) & 3)) << 3);
}
__device__ __forceinline__ int swz64(int row, int slot) {
    return row * 64 + ((slot ^ (row & 7)) << 3);
}

// bijective XCD-chunked block swizzle (m204)
__device__ __forceinline__ int xcd_swz(int lid, int nwg) {
    const int q = nwg >> 3, r = nwg & 7;
    const int xcd = lid & 7, pos = lid >> 3;
    return (xcd < r ? xcd * (q + 1) : r * (q + 1) + (xcd - r) * q) + pos;
}

// GEMM1: x = hs @ wdt^T (f32 A, inline cvt), dense bf16 output + voxel-list
// append (n0==0 blocks). BM=32, BN=96, BK=64 (18 steps), 4 waves (2x2),
// double-buffered LDS, 2-deep register prefetch, one barrier per K-step.
__global__ __launch_bounds__(256) void k_gemm1(const float* __restrict__ A,
                                               const unsigned short* __restrict__ Bt,
                                               const int* __restrict__ coords,
                                               int* __restrict__ cnt_i,
                                               int* __restrict__ vox_pts,
                                               unsigned short* __restrict__ xout,
                                               int M, int N, int K) {
    __shared__ unsigned short As[2][32 * 64];   // 4 KB each
    __shared__ unsigned short Bs[2][96 * 64];   // 12 KB each

    const int tid  = threadIdx.x;
    const int lane = tid & 63;
    const int wave = tid >> 6;
    const int wm   = wave >> 1;
    const int wn   = wave & 1;

    const int nwg = gridDim.x * gridDim.y;
    int lid = xcd_swz(blockIdx.y * gridDim.x + blockIdx.x, nwg);
    const int m0 = (lid / gridDim.x) * 32;
    const int n0 = (lid % gridDim.x) * 96;

    const int  a_row  = tid >> 3;
    const int  a_slot = tid & 7;
    const bool avalid = (m0 + a_row) < M;
    const int  b_row  = tid >> 3;
    const int  b_slot = tid & 7;

    float4 af0, af1;
    short8 breg[3];

    auto LOAD = [&](int kt) {
        const int kb = kt * 64;
        af0 = make_float4(0.f, 0.f, 0.f, 0.f);
        af1 = af0;
        if (avalid) {
            const float* p = A + (size_t)(m0 + a_row) * K + kb + a_slot * 8;
            af0 = *reinterpret_cast<const float4*>(p);
            af1 = *reinterpret_cast<const float4*>(p + 4);
        }
#pragma unroll
        for (int i = 0; i < 3; ++i)
            breg[i] = *reinterpret_cast<const short8*>(
                Bt + (size_t)(n0 + b_row + i * 32) * K + kb + b_slot * 8);
    };

    auto STAGE = [&](int buf) {
        short8 h;
        h[0] = (short)f2bf(af0.x); h[1] = (short)f2bf(af0.y);
        h[2] = (short)f2bf(af0.z); h[3] = (short)f2bf(af0.w);
        h[4] = (short)f2bf(af1.x); h[5] = (short)f2bf(af1.y);
        h[6] = (short)f2bf(af1.z); h[7] = (short)f2bf(af1.w);
        *reinterpret_cast<short8*>(&As[buf][swz64(a_row, a_slot)]) = h;
#pragma unroll
        for (int i = 0; i < 3; ++i)
            *reinterpret_cast<short8*>(&Bs[buf][swz64(b_row + i * 32, b_slot)]) = breg[i];
    };

    f32x4 acc[3];
#pragma unroll
    for (int n = 0; n < 3; ++n) acc[n] = (f32x4){0.f, 0.f, 0.f, 0.f};

    const int nsteps = K / 64;      // 18
    LOAD(0);
    STAGE(0);
    LOAD(1);
    __syncthreads();

    const int kgrp = lane >> 4;
    const int lr   = lane & 15;

    for (int kt = 0; kt < nsteps; ++kt) {
        const int cur = kt & 1;
        short8 af[2], bf_[2][3];
#pragma unroll
        for (int s = 0; s < 2; ++s) {
            af[s] = *reinterpret_cast<const short8*>(
                &As[cur][swz64(wm * 16 + lr, s * 4 + kgrp)]);
#pragma unroll
            for (int n = 0; n < 3; ++n)
                bf_[s][n] = *reinterpret_cast<const short8*>(
                    &Bs[cur][swz64(wn * 48 + n * 16 + lr, s * 4 + kgrp)]);
        }
        if (kt + 1 < nsteps) {
            STAGE(cur ^ 1);
            if (kt + 2 < nsteps) LOAD(kt + 2);
        }
#pragma unroll
        for (int s = 0; s < 2; ++s)
#pragma unroll
            for (int n = 0; n < 3; ++n)
                acc[n] = __builtin_amdgcn_mfma_f32_16x16x32_bf16(af[s], bf_[s][n], acc[n], 0, 0, 0);
        if (kt + 1 < nsteps) __syncthreads();
    }

    const int rq = lane >> 4;
    const int rbase = m0 + wm * 16 + rq * 4;
#pragma unroll
    for (int n = 0; n < 3; ++n) {
        int col = n0 + wn * 48 + n * 16 + lr;
#pragma unroll
        for (int r = 0; r < 4; ++r) {
            int row = rbase + r;
            if (row < M) xout[(size_t)row * N + col] = f2bf(acc[n][r]);
        }
    }
    if (n0 == 0 && wn == 0 && lr == 0) {
#pragma unroll
        for (int r = 0; r < 4; ++r) {
            int row = rbase + r;
            if (row < M) {
                int c0 = coords[row * 3 + 0], c1 = coords[row * 3 + 1],
                    c2 = coords[row * 3 + 2];
                int fl = (c0 * GV + c1) * GV + c2;
                int slot = atomicAdd(&cnt_i[fl], 1);
                if (slot < MAXP) vox_pts[fl * MAXP + slot] = row;
            }
        }
    }
}

// GEMM2 with conv2 fused into the prologue (r7 retried with the r16 conv2
// pattern: w2 staged lane-major in LDS, short8 ptf loads). The full 64x288
// bf16 A-panel lives in LDS (ASTR=292 pad -> 2-way-free fragment reads), so
// the 9-step K-loop only double-buffers B.  out = hs + conv2(ptf) @ wut^T.
constexpr int ASTR = 292;
__global__ __launch_bounds__(256) void k_gemm2f(const unsigned short* __restrict__ ptf,
                                                const float* __restrict__ w2,
                                                const unsigned short* __restrict__ Bt,
                                                const float* __restrict__ Cin,
                                                float* __restrict__ Cout,
                                                int M, int N, int K) {
    __shared__ unsigned short Asf[64 * ASTR];   // 36.5 KB
    __shared__ unsigned short Bs[2][96 * 32];   // 6 KB each
    __shared__ float w2s[8 * 9 * 36];           // 10.1 KB

    const int tid  = threadIdx.x;
    const int lane = tid & 63;
    const int wave = tid >> 6;
    const int wm   = wave >> 1;
    const int wn   = wave & 1;

    const int nwg = gridDim.x * gridDim.y;
    int lid = xcd_swz(blockIdx.y * gridDim.x + blockIdx.x, nwg);
    const int m0 = (lid / gridDim.x) * 64;
    const int n0 = (lid % gridDim.x) * 96;

    const int b0_row = tid >> 2, b0_slot = tid & 3;
    const int b1_row = 64 + (tid >> 2);
    const bool has_b1 = (tid < 128);
    short8 breg0, breg1;

    auto LOADB = [&](int kt) {
        const int kb = kt * 32;
        breg0 = *reinterpret_cast<const short8*>(Bt + (size_t)(n0 + b0_row) * K + kb + b0_slot * 8);
        if (has_b1)
            breg1 = *reinterpret_cast<const short8*>(Bt + (size_t)(n0 + b1_row) * K + kb + b0_slot * 8);
    };
    auto STAGEB = [&](int buf) {
        *reinterpret_cast<short8*>(&Bs[buf][swz(b0_row, b0_slot)]) = breg0;
        if (has_b1)
            *reinterpret_cast<short8*>(&Bs[buf][swz(b1_row, b0_slot)]) = breg1;
    };

    // issue first B loads, then stage w2 lane-major
    LOADB(0);
    for (int i = tid; i < 8 * 9 * 36; i += 256) {
        int c = i / (9 * 36), r = i % (9 * 36), tap = r / 36, s = r % 36;
        w2s[i] = w2[(s * 8 + c) * 9 + tap];
    }
    __syncthreads();    // w2s ready

    // conv2 prologue: 64 rows x 36 ch8-slots = 2304 units, 9 per thread
#pragma unroll
    for (int i = 0; i < 9; ++i) {
        int u = tid + i * 256;
        int r = u / 36, c8 = u % 36;
        int row = m0 + r;
        float acc8[8] = {0.f, 0.f, 0.f, 0.f, 0.f, 0.f, 0.f, 0.f};
        if (row < M) {
            int v = row / L, rem = row - v * L, y = rem / NW, x = rem - y * NW;
#pragma unroll
            for (int dy = 0; dy < 3; ++dy) {
                int yy = y + dy - 1;
                if ((unsigned)yy >= (unsigned)NH) continue;
#pragma unroll
                for (int dx = 0; dx < 3; ++dx) {
                    int xx = x + dx - 1;
                    if ((unsigned)xx >= (unsigned)NW) continue;
                    short8 d = *reinterpret_cast<const short8*>(
                        ptf + ((size_t)v * L + yy * NW + xx) * CD + c8 * 8);
                    int tap = dy * 3 + dx;
#pragma unroll
                    for (int c = 0; c < 8; ++c)
                        acc8[c] += w2s[(c * 9 + tap) * 36 + c8] *
                                   bf2f((unsigned short)d[c]);
                }
            }
        }
        short8 h;
#pragma unroll
        for (int c = 0; c < 8; ++c) h[c] = (short)f2bf(acc8[c]);
        *reinterpret_cast<short8*>(&Asf[r * ASTR + c8 * 8]) = h;
    }

    STAGEB(0);
    LOADB(1);

    f32x4 acc[2][3];
#pragma unroll
    for (int m = 0; m < 2; ++m)
#pragma unroll
        for (int n = 0; n < 3; ++n) acc[m][n] = (f32x4){0.f, 0.f, 0.f, 0.f};

    __syncthreads();    // Asf + Bs[0] ready

    const int kgrp = lane >> 4;
    const int lr   = lane & 15;
    const int nsteps = K / 32;      // 9

    for (int kt = 0; kt < nsteps; ++kt) {
        const int cur = kt & 1;
        short8 afrag[2], bfrag[3];
#pragma unroll
        for (int m = 0; m < 2; ++m)
            afrag[m] = *reinterpret_cast<const short8*>(
                &Asf[(wm * 32 + m * 16 + lr) * ASTR + kt * 32 + kgrp * 8]);
#pragma unroll
        for (int n = 0; n < 3; ++n) {
            int c = wn * 48 + n * 16 + lr;
            bfrag[n] = *reinterpret_cast<const short8*>(&Bs[cur][swz(c, kgrp)]);
        }
        if (kt + 1 < nsteps) {
            STAGEB(cur ^ 1);
            if (kt + 2 < nsteps) LOADB(kt + 2);
        }
#pragma unroll
        for (int m = 0; m < 2; ++m)
#pragma unroll
            for (int n = 0; n < 3; ++n)
                acc[m][n] = __builtin_amdgcn_mfma_f32_16x16x32_bf16(
                    afrag[m], bfrag[n], acc[m][n], 0, 0, 0);
        if (kt + 1 < nsteps) __syncthreads();
    }

    const int rq = lane >> 4;
#pragma unroll
    for (int m = 0; m < 2; ++m) {
        int rbase = m0 + wm * 32 + m * 16 + rq * 4;
#pragma unroll
        for (int n = 0; n < 3; ++n) {
            int col = n0 + wn * 48 + n * 16 + lr;
#pragma unroll
            for (int r = 0; r < 4; ++r) {
                int row = rbase + r;
                if (row < M)
                    Cout[(size_t)row * N + col] =
                        acc[m][n][r] + Cin[(size_t)row * N + col];
            }
        }
    }
}

}  // namespace

extern "C" void kernel_launch(void* const* d_in, const int* in_sizes, int n_in,
                              void* d_out, int out_size, void* d_ws, size_t ws_size,
                              hipStream_t stream) {
    const float* hs     = (const float*)d_in[0];
    const int*   coords = (const int*)d_in[1];
    const float* w_down = (const float*)d_in[2];
    const float* w3     = (const float*)d_in[3];
    const float* w2     = (const float*)d_in[4];
    const float* w_up   = (const float*)d_in[5];
    float* out = (float*)d_out;

    int* cnt_i   = (int*)d_ws;                          // NVOX int
    int* vox_pts = cnt_i + NVOX;                        // NVOX*MAXP int
    unsigned short* xbuf = (unsigned short*)(vox_pts + (size_t)NVOX * MAXP); // NPTS*CD
    unsigned short* ptf  = xbuf + (size_t)NPTS * CD;    // NPTS*CD bf16
    unsigned short* wdt  = ptf + (size_t)NPTS * CD;     // [CD][C] bf16
    unsigned short* wut  = wdt + (size_t)CD * C;        // [C][CD] bf16
    float* w3t = (float*)(wut + (size_t)C * CD);        // [27][288] f32

    // 1. prep: weight transposes + zero cnt_i + w3 transpose
    k_combo<<<dim3(NB_ALL), dim3(256), 0, stream>>>(
        w_down, w_up, w3, wdt, wut, w3t, cnt_i);

    // 2. GEMM1: dense bf16 x + voxel point-list build
    k_gemm1<<<dim3(CD / 96, (NPTS + 31) / 32), dim3(256), 0, stream>>>(
        hs, wdt, coords, cnt_i, vox_pts, xbuf, NPTS, CD, C);

    // 3. depthwise conv3d (vectorized, 7 pts/block, entry lists) + gelu
    k_conv3<<<dim3((NPTS + C3_PTS - 1) / C3_PTS), dim3(256), 0, stream>>>(
        coords, xbuf, cnt_i, vox_pts, w3t, ptf);

    // 4. GEMM2 with fused conv2 prologue: out = hs + conv2(ptf) @ w_up
    k_gemm2f<<<dim3(C / 96, (NPTS + 63) / 64), dim3(256), 0, stream>>>(
        ptf, w2, wut, hs, out, NPTS, C, CD);
}

// Round 18
// 70.767 us; speedup vs baseline: 1.7370x; 1.7370x over previous
//
#include <hip/hip_runtime.h>

namespace {

constexpr int GV   = 48;
constexpr int NV   = 8;
constexpr int NH   = 27;
constexpr int NW   = 27;
constexpr int L    = NH * NW;     // 729
constexpr int C    = 1152;
constexpr int CD   = 288;
constexpr int NPTS = NV * L;      // 5832
constexpr int NVOX = GV * GV * GV;// 110592
constexpr int MAXP = 16;          // max recorded points per voxel

typedef __attribute__((ext_vector_type(8))) short short8;
typedef __attribute__((ext_vector_type(4))) float f32x4;

__device__ __forceinline__ unsigned short f2bf(float x) {
    unsigned u = __float_as_uint(x);
    unsigned r = u + 0x7fffu + ((u >> 16) & 1u);   // round-to-nearest-even
    return (unsigned short)(r >> 16);
}
__device__ __forceinline__ float bf2f(unsigned short h) {
    return __uint_as_float(((unsigned)h) << 16);
}

// ---- combo: weight transposes + cnt_i zero + w3 j-major transpose ----------
constexpr int NB_T   = (C / 32) * (CD / 32);          // 324 per matrix
constexpr int NB_ZC  = (NVOX / 4 + 255) / 256;        // 108 (int4/thread)
constexpr int NB_W3  = 8;                             // 7776 floats / 972
constexpr int B_ZC   = 2 * NB_T;                      // 648
constexpr int B_W3   = B_ZC + NB_ZC;                  // 756
constexpr int NB_ALL = B_W3 + NB_W3;                  // 764

__global__ __launch_bounds__(256) void k_combo(const float* __restrict__ w_down,
                                               const float* __restrict__ w_up,
                                               const float* __restrict__ w3,
                                               unsigned short* __restrict__ wdt,
                                               unsigned short* __restrict__ wut,
                                               float* __restrict__ w3t,
                                               int* __restrict__ cnt_i) {
    const int b   = blockIdx.x;
    const int tid = threadIdx.x;
    if (b < B_ZC) {
        __shared__ float t[32][33];
        const float* W; unsigned short* Wt; int K, N, kb, nb;
        if (b < NB_T) {
            W = w_down; Wt = wdt; K = C; N = CD;
            kb = (b % (C / 32)) * 32; nb = (b / (C / 32)) * 32;
        } else {
            int bb = b - NB_T;
            W = w_up; Wt = wut; K = CD; N = C;
            nb = (bb % (C / 32)) * 32; kb = (bb / (C / 32)) * 32;
        }
#pragma unroll
        for (int i = 0; i < 4; ++i) {
            int r = (tid >> 5) + i * 8, c = tid & 31;
            t[r][c] = W[(size_t)(kb + r) * N + nb + c];
        }
        __syncthreads();
#pragma unroll
        for (int i = 0; i < 4; ++i) {
            int r = (tid >> 5) + i * 8, c = tid & 31;
            Wt[(size_t)(nb + r) * K + kb + c] = f2bf(t[c][r]);
        }
    } else if (b < B_W3) {
        int i = (b - B_ZC) * 256 + tid;
        if (i < NVOX / 4)
            reinterpret_cast<int4*>(cnt_i)[i] = make_int4(0, 0, 0, 0);
    } else {
        int base = (b - B_W3) * 972;
        for (int k = tid; k < 972; k += 256) {
            int d = base + k;              // d < 7776
            int j = d / 288, ch = d % 288;
            w3t[d] = w3[ch * 27 + j];
        }
    }
}

__device__ __forceinline__ float gelu_tanh(float a) {
    float a3 = a * a * a;
    float inner = 0.7978845608028654f * (a + 0.044715f * a3);
    return 0.5f * a * (1.0f + tanhf(inner));
}

// Depthwise 3x3x3 conv at gathered voxels, vectorized: 7 points/block,
// 36 lanes/point, short8 x-loads, float4 w3t loads, per-point entry lists.
constexpr int C3_PTS = 7;
__global__ __launch_bounds__(256) void k_conv3(const int* __restrict__ coords,
                                               const unsigned short* __restrict__ x,
                                               const int* __restrict__ cnt_i,
                                               const int* __restrict__ vox_pts,
                                               const float* __restrict__ w3t,
                                               unsigned short* __restrict__ ptf) {
    __shared__ int   ent_pj[C3_PTS][27 * MAXP];
    __shared__ float ent_r[C3_PTS][27 * MAXP];
    __shared__ int   nent[C3_PTS];
    const int tid = threadIdx.x;
    const int p0  = blockIdx.x * C3_PTS;
    if (tid < C3_PTS) nent[tid] = 0;
    __syncthreads();
    if (tid < C3_PTS * 27) {
        int pp = tid / 27, j = tid - pp * 27;
        int p  = p0 + pp;
        if (p < NPTS) {
            int dz = j / 9, rem = j - dz * 9, dy = rem / 3, dx = rem - dy * 3;
            int c0 = coords[p * 3 + 0], c1 = coords[p * 3 + 1], c2 = coords[p * 3 + 2];
            int z = c0 + dz - 1, y = c1 + dy - 1, x2 = c2 + dx - 1;
            if ((unsigned)z < (unsigned)GV && (unsigned)y < (unsigned)GV &&
                (unsigned)x2 < (unsigned)GV) {
                int n = (z * GV + y) * GV + x2;
                int c = cnt_i[n];
                if (c > 0) {
                    int cc = c < MAXP ? c : MAXP;
                    float r = 1.0f / (float)c;
                    int base = atomicAdd(&nent[pp], cc);
                    for (int q = 0; q < cc; ++q) {
                        ent_pj[pp][base + q] = (vox_pts[n * MAXP + q] << 5) | j;
                        ent_r[pp][base + q]  = r;
                    }
                }
            }
        }
    }
    __syncthreads();
    const int pp = tid / 36, s = tid % 36;
    const int p  = p0 + pp;
    if (pp >= C3_PTS || p >= NPTS) return;
    const int ne = nent[pp];
    float acc[8] = {0.f, 0.f, 0.f, 0.f, 0.f, 0.f, 0.f, 0.f};
    for (int i = 0; i < ne; ++i) {
        int e  = ent_pj[pp][i];
        int p2 = e >> 5, j = e & 31;
        float r = ent_r[pp][i];
        short8 d = *reinterpret_cast<const short8*>(x + (size_t)p2 * CD + s * 8);
        const float4* wp = reinterpret_cast<const float4*>(w3t + j * 288 + s * 8);
        float4 w0 = wp[0], w1 = wp[1];
        acc[0] += w0.x * r * bf2f((unsigned short)d[0]);
        acc[1] += w0.y * r * bf2f((unsigned short)d[1]);
        acc[2] += w0.z * r * bf2f((unsigned short)d[2]);
        acc[3] += w0.w * r * bf2f((unsigned short)d[3]);
        acc[4] += w1.x * r * bf2f((unsigned short)d[4]);
        acc[5] += w1.y * r * bf2f((unsigned short)d[5]);
        acc[6] += w1.z * r * bf2f((unsigned short)d[6]);
        acc[7] += w1.w * r * bf2f((unsigned short)d[7]);
    }
    short8 h;
#pragma unroll
    for (int c = 0; c < 8; ++c) h[c] = (short)f2bf(gelu_tanh(acc[c]));
    *reinterpret_cast<short8*>(ptf + (size_t)p * CD + s * 8) = h;
}

// Depthwise 3x3 conv2d, vectorized: 256 threads, 7 points/block, 36 lanes per
// point, short8 (8ch) per lane. w2 staged in LDS lane-major (conflict-free).
constexpr int C2_PTS = 7;
__global__ __launch_bounds__(256) void k_conv2(const unsigned short* __restrict__ ptf,
                                               const float* __restrict__ w2,
                                               unsigned short* __restrict__ sm) {
    __shared__ float w2s[8 * 9 * 36];     // 10368 B
    const int tid = threadIdx.x;
    for (int i = tid; i < 8 * 9 * 36; i += 256) {
        int c = i / (9 * 36), r = i % (9 * 36), tap = r / 36, s = r % 36;
        w2s[i] = w2[(s * 8 + c) * 9 + tap];
    }
    __syncthreads();
    const int pp = tid / 36, s = tid % 36;
    const int p  = blockIdx.x * C2_PTS + pp;
    if (pp >= C2_PTS || p >= NPTS) return;
    int v = p / L, rem = p - v * L, y = rem / NW, x = rem - y * NW;
    float acc[8] = {0.f, 0.f, 0.f, 0.f, 0.f, 0.f, 0.f, 0.f};
#pragma unroll
    for (int dy = 0; dy < 3; ++dy) {
        int yy = y + dy - 1;
        if ((unsigned)yy >= (unsigned)NH) continue;
#pragma unroll
        for (int dx = 0; dx < 3; ++dx) {
            int xx = x + dx - 1;
            if ((unsigned)xx >= (unsigned)NW) continue;
            short8 d = *reinterpret_cast<const short8*>(
                ptf + ((size_t)v * L + yy * NW + xx) * CD + s * 8);
            int tap = dy * 3 + dx;
#pragma unroll
            for (int c = 0; c < 8; ++c)
                acc[c] += w2s[(c * 9 + tap) * 36 + s] * bf2f((unsigned short)d[c]);
        }
    }
    short8 h;
#pragma unroll
    for (int c = 0; c < 8; ++c) h[c] = (short)f2bf(acc[c]);
    *reinterpret_cast<short8*>(sm + (size_t)p * CD + s * 8) = h;
}

// LDS swizzles: [rows][32] and [rows][64] bf16 tiles, slot = 16B unit.
__device__ __forceinline__ int swz(int row, int slot) {
    return row * 32 + ((slot ^ ((row >> 1) & 3)) << 3);
}
__device__ __forceinline__ int swz64(int row, int slot) {
    return row * 64 + ((slot ^ (row & 7)) << 3);
}

// bijective XCD-chunked block swizzle (m204)
__device__ __forceinline__ int xcd_swz(int lid, int nwg) {
    const int q = nwg >> 3, r = nwg & 7;
    const int xcd = lid & 7, pos = lid >> 3;
    return (xcd < r ? xcd * (q + 1) : r * (q + 1) + (xcd - r) * q) + pos;
}

// GEMM1: x = hs @ wdt^T (f32 A, inline cvt), dense bf16 output + voxel-list
// append (n0==0 blocks). BM=32, BN=96, BK=64 (18 steps), 4 waves (2x2),
// double-buffered LDS, 2-deep register prefetch, one barrier per K-step.
__global__ __launch_bounds__(256) void k_gemm1(const float* __restrict__ A,
                                               const unsigned short* __restrict__ Bt,
                                               const int* __restrict__ coords,
                                               int* __restrict__ cnt_i,
                                               int* __restrict__ vox_pts,
                                               unsigned short* __restrict__ xout,
                                               int M, int N, int K) {
    __shared__ unsigned short As[2][32 * 64];   // 4 KB each
    __shared__ unsigned short Bs[2][96 * 64];   // 12 KB each

    const int tid  = threadIdx.x;
    const int lane = tid & 63;
    const int wave = tid >> 6;
    const int wm   = wave >> 1;
    const int wn   = wave & 1;

    const int nwg = gridDim.x * gridDim.y;
    int lid = xcd_swz(blockIdx.y * gridDim.x + blockIdx.x, nwg);
    const int m0 = (lid / gridDim.x) * 32;
    const int n0 = (lid % gridDim.x) * 96;

    const int  a_row  = tid >> 3;
    const int  a_slot = tid & 7;
    const bool avalid = (m0 + a_row) < M;
    const int  b_row  = tid >> 3;
    const int  b_slot = tid & 7;

    float4 af0, af1;
    short8 breg[3];

    auto LOAD = [&](int kt) {
        const int kb = kt * 64;
        af0 = make_float4(0.f, 0.f, 0.f, 0.f);
        af1 = af0;
        if (avalid) {
            const float* p = A + (size_t)(m0 + a_row) * K + kb + a_slot * 8;
            af0 = *reinterpret_cast<const float4*>(p);
            af1 = *reinterpret_cast<const float4*>(p + 4);
        }
#pragma unroll
        for (int i = 0; i < 3; ++i)
            breg[i] = *reinterpret_cast<const short8*>(
                Bt + (size_t)(n0 + b_row + i * 32) * K + kb + b_slot * 8);
    };

    auto STAGE = [&](int buf) {
        short8 h;
        h[0] = (short)f2bf(af0.x); h[1] = (short)f2bf(af0.y);
        h[2] = (short)f2bf(af0.z); h[3] = (short)f2bf(af0.w);
        h[4] = (short)f2bf(af1.x); h[5] = (short)f2bf(af1.y);
        h[6] = (short)f2bf(af1.z); h[7] = (short)f2bf(af1.w);
        *reinterpret_cast<short8*>(&As[buf][swz64(a_row, a_slot)]) = h;
#pragma unroll
        for (int i = 0; i < 3; ++i)
            *reinterpret_cast<short8*>(&Bs[buf][swz64(b_row + i * 32, b_slot)]) = breg[i];
    };

    f32x4 acc[3];
#pragma unroll
    for (int n = 0; n < 3; ++n) acc[n] = (f32x4){0.f, 0.f, 0.f, 0.f};

    const int nsteps = K / 64;      // 18
    LOAD(0);
    STAGE(0);
    LOAD(1);
    __syncthreads();

    const int kgrp = lane >> 4;
    const int lr   = lane & 15;

    for (int kt = 0; kt < nsteps; ++kt) {
        const int cur = kt & 1;
        short8 af[2], bf_[2][3];
#pragma unroll
        for (int s = 0; s < 2; ++s) {
            af[s] = *reinterpret_cast<const short8*>(
                &As[cur][swz64(wm * 16 + lr, s * 4 + kgrp)]);
#pragma unroll
            for (int n = 0; n < 3; ++n)
                bf_[s][n] = *reinterpret_cast<const short8*>(
                    &Bs[cur][swz64(wn * 48 + n * 16 + lr, s * 4 + kgrp)]);
        }
        if (kt + 1 < nsteps) {
            STAGE(cur ^ 1);
            if (kt + 2 < nsteps) LOAD(kt + 2);
        }
#pragma unroll
        for (int s = 0; s < 2; ++s)
#pragma unroll
            for (int n = 0; n < 3; ++n)
                acc[n] = __builtin_amdgcn_mfma_f32_16x16x32_bf16(af[s], bf_[s][n], acc[n], 0, 0, 0);
        if (kt + 1 < nsteps) __syncthreads();
    }

    const int rq = lane >> 4;
    const int rbase = m0 + wm * 16 + rq * 4;
#pragma unroll
    for (int n = 0; n < 3; ++n) {
        int col = n0 + wn * 48 + n * 16 + lr;
#pragma unroll
        for (int r = 0; r < 4; ++r) {
            int row = rbase + r;
            if (row < M) xout[(size_t)row * N + col] = f2bf(acc[n][r]);
        }
    }
    if (n0 == 0 && wn == 0 && lr == 0) {
#pragma unroll
        for (int r = 0; r < 4; ++r) {
            int row = rbase + r;
            if (row < M) {
                int c0 = coords[row * 3 + 0], c1 = coords[row * 3 + 1],
                    c2 = coords[row * 3 + 2];
                int fl = (c0 * GV + c1) * GV + c2;
                int slot = atomicAdd(&cnt_i[fl], 1);
                if (slot < MAXP) vox_pts[fl * MAXP + slot] = row;
            }
        }
    }
}

// GEMM2: out = hs + A @ Bt^T, A-fragments DIRECT from global (A is L2-resident
// smbuf; each lane reads its own row's 16B, double-buffered in registers so the
// per-step barrier drain completes them). LDS holds only B (12 KB). Dims are
// compile-time (M=NPTS, N=C, K=CD) so the 9-step loop fully unrolls.
__global__ __launch_bounds__(256) void k_gemm2(const unsigned short* __restrict__ A,
                                               const unsigned short* __restrict__ Bt,
                                               const float* __restrict__ Cin,
                                               float* __restrict__ Cout) {
    constexpr int M = NPTS, N = C, K = CD;
    constexpr int nsteps = K / 32;              // 9
    __shared__ unsigned short Bs[2][96 * 32];   // 6 KB each

    const int tid  = threadIdx.x;
    const int lane = tid & 63;
    const int wave = tid >> 6;
    const int wm   = wave >> 1;
    const int wn   = wave & 1;

    const int nwg = gridDim.x * gridDim.y;
    int lid = xcd_swz(blockIdx.y * gridDim.x + blockIdx.x, nwg);
    const int m0 = (lid / gridDim.x) * 64;
    const int n0 = (lid % gridDim.x) * 96;

    const int kgrp = lane >> 4;
    const int lr   = lane & 15;

    // per-lane A rows (wave-tile rows wm*32 + {0,16} + lr)
    const int arow0 = m0 + wm * 32 + lr;
    const int arow1 = arow0 + 16;
    const bool av0 = arow0 < M, av1 = arow1 < M;
    const unsigned short* ap0 = A + (size_t)arow0 * K + kgrp * 8;
    const unsigned short* ap1 = A + (size_t)arow1 * K + kgrp * 8;

    const int b0_row = tid >> 2, b0_slot = tid & 3;
    const int b1_row = 64 + (tid >> 2);
    const bool has_b1 = (tid < 128);
    short8 breg0, breg1;

    auto LOADB = [&](int kt) {
        const int kb = kt * 32;
        breg0 = *reinterpret_cast<const short8*>(Bt + (size_t)(n0 + b0_row) * K + kb + b0_slot * 8);
        if (has_b1)
            breg1 = *reinterpret_cast<const short8*>(Bt + (size_t)(n0 + b1_row) * K + kb + b0_slot * 8);
    };
    auto STAGEB = [&](int buf) {
        *reinterpret_cast<short8*>(&Bs[buf][swz(b0_row, b0_slot)]) = breg0;
        if (has_b1)
            *reinterpret_cast<short8*>(&Bs[buf][swz(b1_row, b0_slot)]) = breg1;
    };

    const short8 zero8 = (short8){0, 0, 0, 0, 0, 0, 0, 0};
    short8 afc[2], afn[2];

    // prologue: B tile 0 staged; B tile 1 in regs; A frags for step 0 in regs
    LOADB(0);
    STAGEB(0);
    LOADB(1);
    afc[0] = av0 ? *reinterpret_cast<const short8*>(ap0) : zero8;
    afc[1] = av1 ? *reinterpret_cast<const short8*>(ap1) : zero8;
    __syncthreads();

    f32x4 acc[2][3];
#pragma unroll
    for (int m = 0; m < 2; ++m)
#pragma unroll
        for (int n = 0; n < 3; ++n) acc[m][n] = (f32x4){0.f, 0.f, 0.f, 0.f};

#pragma unroll
    for (int kt = 0; kt < nsteps; ++kt) {
        const int cur = kt & 1;
        short8 bfrag[3];
#pragma unroll
        for (int n = 0; n < 3; ++n) {
            int c = wn * 48 + n * 16 + lr;
            bfrag[n] = *reinterpret_cast<const short8*>(&Bs[cur][swz(c, kgrp)]);
        }
        // prefetch next-step A frags + B staging before the barrier drain
        if (kt + 1 < nsteps) {
            const int kb = (kt + 1) * 32;
            afn[0] = av0 ? *reinterpret_cast<const short8*>(ap0 + kb) : zero8;
            afn[1] = av1 ? *reinterpret_cast<const short8*>(ap1 + kb) : zero8;
            STAGEB(cur ^ 1);
            if (kt + 2 < nsteps) LOADB(kt + 2);
        }
#pragma unroll
        for (int m = 0; m < 2; ++m)
#pragma unroll
            for (int n = 0; n < 3; ++n)
                acc[m][n] = __builtin_amdgcn_mfma_f32_16x16x32_bf16(
                    afc[m], bfrag[n], acc[m][n], 0, 0, 0);
        if (kt + 1 < nsteps) {
            afc[0] = afn[0];
            afc[1] = afn[1];
            __syncthreads();
        }
    }

    const int rq = lane >> 4;
#pragma unroll
    for (int m = 0; m < 2; ++m) {
        int rbase = m0 + wm * 32 + m * 16 + rq * 4;
#pragma unroll
        for (int n = 0; n < 3; ++n) {
            int col = n0 + wn * 48 + n * 16 + lr;
#pragma unroll
            for (int r = 0; r < 4; ++r) {
                int row = rbase + r;
                if (row < M)
                    Cout[(size_t)row * N + col] =
                        acc[m][n][r] + Cin[(size_t)row * N + col];
            }
        }
    }
}

}  // namespace

extern "C" void kernel_launch(void* const* d_in, const int* in_sizes, int n_in,
                              void* d_out, int out_size, void* d_ws, size_t ws_size,
                              hipStream_t stream) {
    const float* hs     = (const float*)d_in[0];
    const int*   coords = (const int*)d_in[1];
    const float* w_down = (const float*)d_in[2];
    const float* w3     = (const float*)d_in[3];
    const float* w2     = (const float*)d_in[4];
    const float* w_up   = (const float*)d_in[5];
    float* out = (float*)d_out;

    int* cnt_i   = (int*)d_ws;                          // NVOX int
    int* vox_pts = cnt_i + NVOX;                        // NVOX*MAXP int
    unsigned short* xbuf  = (unsigned short*)(vox_pts + (size_t)NVOX * MAXP); // NPTS*CD
    unsigned short* ptf   = xbuf + (size_t)NPTS * CD;   // NPTS*CD bf16
    unsigned short* smbuf = ptf + (size_t)NPTS * CD;    // NPTS*CD bf16
    unsigned short* wdt   = smbuf + (size_t)NPTS * CD;  // [CD][C] bf16
    unsigned short* wut   = wdt + (size_t)CD * C;       // [C][CD] bf16
    float* w3t = (float*)(wut + (size_t)C * CD);        // [27][288] f32

    // 1. prep: weight transposes + zero cnt_i + w3 transpose
    k_combo<<<dim3(NB_ALL), dim3(256), 0, stream>>>(
        w_down, w_up, w3, wdt, wut, w3t, cnt_i);

    // 2. GEMM1: dense bf16 x + voxel point-list build
    k_gemm1<<<dim3(CD / 96, (NPTS + 31) / 32), dim3(256), 0, stream>>>(
        hs, wdt, coords, cnt_i, vox_pts, xbuf, NPTS, CD, C);

    // 3. depthwise conv3d (vectorized, 7 pts/block, entry lists) + gelu
    k_conv3<<<dim3((NPTS + C3_PTS - 1) / C3_PTS), dim3(256), 0, stream>>>(
        coords, xbuf, cnt_i, vox_pts, w3t, ptf);

    // 4. depthwise conv2d (vectorized, 7 pts/block)
    k_conv2<<<dim3((NPTS + C2_PTS - 1) / C2_PTS), dim3(256), 0, stream>>>(
        ptf, w2, smbuf);

    // 5. out = hs + sm @ w_up  (A-frags direct from L2, B-only LDS pipeline)
    k_gemm2<<<dim3(C / 96, (NPTS + 63) / 64), dim3(256), 0, stream>>>(
        smbuf, wut, hs, out);
}

// Round 19
// 61.333 us; speedup vs baseline: 2.0042x; 1.1538x over previous
//
#include <hip/hip_runtime.h>

namespace {

constexpr int GV   = 48;
constexpr int NV   = 8;
constexpr int NH   = 27;
constexpr int NW   = 27;
constexpr int L    = NH * NW;     // 729
constexpr int C    = 1152;
constexpr int CD   = 288;
constexpr int NPTS = NV * L;      // 5832
constexpr int NVOX = GV * GV * GV;// 110592
constexpr int MAXP = 16;          // max recorded points per voxel

typedef __attribute__((ext_vector_type(8))) short short8;
typedef __attribute__((ext_vector_type(4))) float f32x4;

__device__ __forceinline__ unsigned short f2bf(float x) {
    unsigned u = __float_as_uint(x);
    unsigned r = u + 0x7fffu + ((u >> 16) & 1u);   // round-to-nearest-even
    return (unsigned short)(r >> 16);
}
__device__ __forceinline__ float bf2f(unsigned short h) {
    return __uint_as_float(((unsigned)h) << 16);
}

// ---- combo: weight transposes + cnt_i zero + w3 j-major transpose ----------
constexpr int NB_T   = (C / 32) * (CD / 32);          // 324 per matrix
constexpr int NB_ZC  = (NVOX / 4 + 255) / 256;        // 108 (int4/thread)
constexpr int NB_W3  = 8;                             // 7776 floats / 972
constexpr int B_ZC   = 2 * NB_T;                      // 648
constexpr int B_W3   = B_ZC + NB_ZC;                  // 756
constexpr int NB_ALL = B_W3 + NB_W3;                  // 764

__global__ __launch_bounds__(256) void k_combo(const float* __restrict__ w_down,
                                               const float* __restrict__ w_up,
                                               const float* __restrict__ w3,
                                               unsigned short* __restrict__ wdt,
                                               unsigned short* __restrict__ wut,
                                               float* __restrict__ w3t,
                                               int* __restrict__ cnt_i) {
    const int b   = blockIdx.x;
    const int tid = threadIdx.x;
    if (b < B_ZC) {
        __shared__ float t[32][33];
        const float* W; unsigned short* Wt; int K, N, kb, nb;
        if (b < NB_T) {
            W = w_down; Wt = wdt; K = C; N = CD;
            kb = (b % (C / 32)) * 32; nb = (b / (C / 32)) * 32;
        } else {
            int bb = b - NB_T;
            W = w_up; Wt = wut; K = CD; N = C;
            nb = (bb % (C / 32)) * 32; kb = (bb / (C / 32)) * 32;
        }
#pragma unroll
        for (int i = 0; i < 4; ++i) {
            int r = (tid >> 5) + i * 8, c = tid & 31;
            t[r][c] = W[(size_t)(kb + r) * N + nb + c];
        }
        __syncthreads();
#pragma unroll
        for (int i = 0; i < 4; ++i) {
            int r = (tid >> 5) + i * 8, c = tid & 31;
            Wt[(size_t)(nb + r) * K + kb + c] = f2bf(t[c][r]);
        }
    } else if (b < B_W3) {
        int i = (b - B_ZC) * 256 + tid;
        if (i < NVOX / 4)
            reinterpret_cast<int4*>(cnt_i)[i] = make_int4(0, 0, 0, 0);
    } else {
        int base = (b - B_W3) * 972;
        for (int k = tid; k < 972; k += 256) {
            int d = base + k;              // d < 7776
            int j = d / 288, ch = d % 288;
            w3t[d] = w3[ch * 27 + j];
        }
    }
}

__device__ __forceinline__ float gelu_tanh(float a) {
    float a3 = a * a * a;
    float inner = 0.7978845608028654f * (a + 0.044715f * a3);
    return 0.5f * a * (1.0f + tanhf(inner));
}

// Depthwise 3x3x3 conv at gathered voxels, vectorized: 7 points/block,
// 36 lanes/point, short8 x-loads, float4 w3t loads, per-point entry lists.
constexpr int C3_PTS = 7;
__global__ __launch_bounds__(256) void k_conv3(const int* __restrict__ coords,
                                               const unsigned short* __restrict__ x,
                                               const int* __restrict__ cnt_i,
                                               const int* __restrict__ vox_pts,
                                               const float* __restrict__ w3t,
                                               unsigned short* __restrict__ ptf) {
    __shared__ int   ent_pj[C3_PTS][27 * MAXP];
    __shared__ float ent_r[C3_PTS][27 * MAXP];
    __shared__ int   nent[C3_PTS];
    const int tid = threadIdx.x;
    const int p0  = blockIdx.x * C3_PTS;
    if (tid < C3_PTS) nent[tid] = 0;
    __syncthreads();
    if (tid < C3_PTS * 27) {
        int pp = tid / 27, j = tid - pp * 27;
        int p  = p0 + pp;
        if (p < NPTS) {
            int dz = j / 9, rem = j - dz * 9, dy = rem / 3, dx = rem - dy * 3;
            int c0 = coords[p * 3 + 0], c1 = coords[p * 3 + 1], c2 = coords[p * 3 + 2];
            int z = c0 + dz - 1, y = c1 + dy - 1, x2 = c2 + dx - 1;
            if ((unsigned)z < (unsigned)GV && (unsigned)y < (unsigned)GV &&
                (unsigned)x2 < (unsigned)GV) {
                int n = (z * GV + y) * GV + x2;
                int c = cnt_i[n];
                if (c > 0) {
                    int cc = c < MAXP ? c : MAXP;
                    float r = 1.0f / (float)c;
                    int base = atomicAdd(&nent[pp], cc);
                    for (int q = 0; q < cc; ++q) {
                        ent_pj[pp][base + q] = (vox_pts[n * MAXP + q] << 5) | j;
                        ent_r[pp][base + q]  = r;
                    }
                }
            }
        }
    }
    __syncthreads();
    const int pp = tid / 36, s = tid % 36;
    const int p  = p0 + pp;
    if (pp >= C3_PTS || p >= NPTS) return;
    const int ne = nent[pp];
    float acc[8] = {0.f, 0.f, 0.f, 0.f, 0.f, 0.f, 0.f, 0.f};
    for (int i = 0; i < ne; ++i) {
        int e  = ent_pj[pp][i];
        int p2 = e >> 5, j = e & 31;
        float r = ent_r[pp][i];
        short8 d = *reinterpret_cast<const short8*>(x + (size_t)p2 * CD + s * 8);
        const float4* wp = reinterpret_cast<const float4*>(w3t + j * 288 + s * 8);
        float4 w0 = wp[0], w1 = wp[1];
        acc[0] += w0.x * r * bf2f((unsigned short)d[0]);
        acc[1] += w0.y * r * bf2f((unsigned short)d[1]);
        acc[2] += w0.z * r * bf2f((unsigned short)d[2]);
        acc[3] += w0.w * r * bf2f((unsigned short)d[3]);
        acc[4] += w1.x * r * bf2f((unsigned short)d[4]);
        acc[5] += w1.y * r * bf2f((unsigned short)d[5]);
        acc[6] += w1.z * r * bf2f((unsigned short)d[6]);
        acc[7] += w1.w * r * bf2f((unsigned short)d[7]);
    }
    short8 h;
#pragma unroll
    for (int c = 0; c < 8; ++c) h[c] = (short)f2bf(gelu_tanh(acc[c]));
    *reinterpret_cast<short8*>(ptf + (size_t)p * CD + s * 8) = h;
}

// Depthwise 3x3 conv2d, vectorized: 256 threads, 7 points/block, 36 lanes per
// point, short8 (8ch) per lane. w2 staged in LDS lane-major (conflict-free).
constexpr int C2_PTS = 7;
__global__ __launch_bounds__(256) void k_conv2(const unsigned short* __restrict__ ptf,
                                               const float* __restrict__ w2,
                                               unsigned short* __restrict__ sm) {
    __shared__ float w2s[8 * 9 * 36];     // 10368 B
    const int tid = threadIdx.x;
    for (int i = tid; i < 8 * 9 * 36; i += 256) {
        int c = i / (9 * 36), r = i % (9 * 36), tap = r / 36, s = r % 36;
        w2s[i] = w2[(s * 8 + c) * 9 + tap];
    }
    __syncthreads();
    const int pp = tid / 36, s = tid % 36;
    const int p  = blockIdx.x * C2_PTS + pp;
    if (pp >= C2_PTS || p >= NPTS) return;
    int v = p / L, rem = p - v * L, y = rem / NW, x = rem - y * NW;
    float acc[8] = {0.f, 0.f, 0.f, 0.f, 0.f, 0.f, 0.f, 0.f};
#pragma unroll
    for (int dy = 0; dy < 3; ++dy) {
        int yy = y + dy - 1;
        if ((unsigned)yy >= (unsigned)NH) continue;
#pragma unroll
        for (int dx = 0; dx < 3; ++dx) {
            int xx = x + dx - 1;
            if ((unsigned)xx >= (unsigned)NW) continue;
            short8 d = *reinterpret_cast<const short8*>(
                ptf + ((size_t)v * L + yy * NW + xx) * CD + s * 8);
            int tap = dy * 3 + dx;
#pragma unroll
            for (int c = 0; c < 8; ++c)
                acc[c] += w2s[(c * 9 + tap) * 36 + s] * bf2f((unsigned short)d[c]);
        }
    }
    short8 h;
#pragma unroll
    for (int c = 0; c < 8; ++c) h[c] = (short)f2bf(acc[c]);
    *reinterpret_cast<short8*>(sm + (size_t)p * CD + s * 8) = h;
}

// LDS swizzles: [rows][32] and [rows][64] bf16 tiles, slot = 16B unit.
__device__ __forceinline__ int swz(int row, int slot) {
    return row * 32 + ((slot ^ ((row >> 1) & 3)) << 3);
}
__device__ __forceinline__ int swz64(int row, int slot) {
    return row * 64 + ((slot ^ (row & 7)) << 3);
}

// bijective XCD-chunked block swizzle (m204)
__device__ __forceinline__ int xcd_swz(int lid, int nwg) {
    const int q = nwg >> 3, r = nwg & 7;
    const int xcd = lid & 7, pos = lid >> 3;
    return (xcd < r ? xcd * (q + 1) : r * (q + 1) + (xcd - r) * q) + pos;
}

// GEMM1: x = hs @ wdt^T (f32 A, inline cvt), dense bf16 output + voxel-list
// append (n0==0 blocks). BM=32, BN=96, BK=64, 4 waves (2x2), double-buffered
// LDS, one barrier per K-step. A prefetch is 3 TILES DEEP (hs is cold HBM,
// ~900cyc; issue->stage lead = 2 K-steps) while B stays 2-deep (wdt is
// L2-resident). Dims constexpr -> 18-step loop fully unrolls, so the 3-slot
// A-register rotation is static (no scratch, rule #20).
__global__ __launch_bounds__(256) void k_gemm1(const float* __restrict__ A,
                                               const unsigned short* __restrict__ Bt,
                                               const int* __restrict__ coords,
                                               int* __restrict__ cnt_i,
                                               int* __restrict__ vox_pts,
                                               unsigned short* __restrict__ xout) {
    constexpr int M = NPTS, N = CD, K = C;
    constexpr int nsteps = K / 64;              // 18
    __shared__ unsigned short As[2][32 * 64];   // 4 KB each
    __shared__ unsigned short Bs[2][96 * 64];   // 12 KB each

    const int tid  = threadIdx.x;
    const int lane = tid & 63;
    const int wave = tid >> 6;
    const int wm   = wave >> 1;
    const int wn   = wave & 1;

    const int nwg = gridDim.x * gridDim.y;
    int lid = xcd_swz(blockIdx.y * gridDim.x + blockIdx.x, nwg);
    const int m0 = (lid / gridDim.x) * 32;
    const int n0 = (lid % gridDim.x) * 96;

    const int  a_row  = tid >> 3;
    const int  a_slot = tid & 7;
    const bool avalid = (m0 + a_row) < M;
    const int  b_row  = tid >> 3;
    const int  b_slot = tid & 7;
    const float* aptr = A + (size_t)(m0 + a_row) * K + a_slot * 8;

    float4 afa[3][2];         // 3-deep A tile slots (static-indexed via unroll)
    short8 breg[3];

    auto LOADA = [&](int kt, int slot) {
        afa[slot][0] = make_float4(0.f, 0.f, 0.f, 0.f);
        afa[slot][1] = afa[slot][0];
        if (avalid) {
            const float* p = aptr + kt * 64;
            afa[slot][0] = *reinterpret_cast<const float4*>(p);
            afa[slot][1] = *reinterpret_cast<const float4*>(p + 4);
        }
    };
    auto LOADB = [&](int kt) {
        const int kb = kt * 64;
#pragma unroll
        for (int i = 0; i < 3; ++i)
            breg[i] = *reinterpret_cast<const short8*>(
                Bt + (size_t)(n0 + b_row + i * 32) * K + kb + b_slot * 8);
    };
    auto STAGE = [&](int buf, int slot) {
        short8 h;
        h[0] = (short)f2bf(afa[slot][0].x); h[1] = (short)f2bf(afa[slot][0].y);
        h[2] = (short)f2bf(afa[slot][0].z); h[3] = (short)f2bf(afa[slot][0].w);
        h[4] = (short)f2bf(afa[slot][1].x); h[5] = (short)f2bf(afa[slot][1].y);
        h[6] = (short)f2bf(afa[slot][1].z); h[7] = (short)f2bf(afa[slot][1].w);
        *reinterpret_cast<short8*>(&As[buf][swz64(a_row, a_slot)]) = h;
#pragma unroll
        for (int i = 0; i < 3; ++i)
            *reinterpret_cast<short8*>(&Bs[buf][swz64(b_row + i * 32, b_slot)]) = breg[i];
    };

    f32x4 acc[3];
#pragma unroll
    for (int n = 0; n < 3; ++n) acc[n] = (f32x4){0.f, 0.f, 0.f, 0.f};

    // prologue: tile0 staged from slot0; tile1 -> slot1; tile2 -> slot2
    LOADA(0, 0);
    LOADB(0);
    STAGE(0, 0);
    LOADA(1, 1);
    LOADB(1);
    LOADA(2, 2);
    __syncthreads();

    const int kgrp = lane >> 4;
    const int lr   = lane & 15;

#pragma unroll
    for (int kt = 0; kt < nsteps; ++kt) {
        const int cur = kt & 1;
        short8 af[2], bf_[2][3];
#pragma unroll
        for (int s = 0; s < 2; ++s) {
            af[s] = *reinterpret_cast<const short8*>(
                &As[cur][swz64(wm * 16 + lr, s * 4 + kgrp)]);
#pragma unroll
            for (int n = 0; n < 3; ++n)
                bf_[s][n] = *reinterpret_cast<const short8*>(
                    &Bs[cur][swz64(wn * 48 + n * 16 + lr, s * 4 + kgrp)]);
        }
        if (kt + 1 < nsteps) {
            STAGE(cur ^ 1, (kt + 1) % 3);      // stage tile kt+1 (A slot + breg)
            if (kt + 2 < nsteps) LOADB(kt + 2);
            if (kt + 3 < nsteps) LOADA(kt + 3, (kt + 3) % 3);
        }
#pragma unroll
        for (int s = 0; s < 2; ++s)
#pragma unroll
            for (int n = 0; n < 3; ++n)
                acc[n] = __builtin_amdgcn_mfma_f32_16x16x32_bf16(af[s], bf_[s][n], acc[n], 0, 0, 0);
        if (kt + 1 < nsteps) __syncthreads();
    }

    const int rq = lane >> 4;
    const int rbase = m0 + wm * 16 + rq * 4;
#pragma unroll
    for (int n = 0; n < 3; ++n) {
        int col = n0 + wn * 48 + n * 16 + lr;
#pragma unroll
        for (int r = 0; r < 4; ++r) {
            int row = rbase + r;
            if (row < M) xout[(size_t)row * N + col] = f2bf(acc[n][r]);
        }
    }
    if (n0 == 0 && wn == 0 && lr == 0) {
#pragma unroll
        for (int r = 0; r < 4; ++r) {
            int row = rbase + r;
            if (row < M) {
                int c0 = coords[row * 3 + 0], c1 = coords[row * 3 + 1],
                    c2 = coords[row * 3 + 2];
                int fl = (c0 * GV + c1) * GV + c2;
                int slot = atomicAdd(&cnt_i[fl], 1);
                if (slot < MAXP) vox_pts[fl * MAXP + slot] = row;
            }
        }
    }
}

// Plain bf16 GEMM2: out = Cin + A @ Bt^T. BM=64, BN=96, BK=32, 4 waves (2x2),
// double-buffered LDS, 2-deep register prefetch, one barrier per K-step.
__global__ __launch_bounds__(256) void k_gemm2(const unsigned short* __restrict__ A,
                                               const unsigned short* __restrict__ Bt,
                                               const float* __restrict__ Cin,
                                               float* __restrict__ Cout,
                                               int M, int N, int K) {
    __shared__ unsigned short As[2][64 * 32];
    __shared__ unsigned short Bs[2][96 * 32];

    const int tid  = threadIdx.x;
    const int lane = tid & 63;
    const int wave = tid >> 6;
    const int wm   = wave >> 1;
    const int wn   = wave & 1;

    const int nwg = gridDim.x * gridDim.y;
    int lid = xcd_swz(blockIdx.y * gridDim.x + blockIdx.x, nwg);
    const int m0 = (lid / gridDim.x) * 64;
    const int n0 = (lid % gridDim.x) * 96;

    const int  a_row  = tid >> 2;
    const int  a_slot = tid & 3;
    const bool avalid = (m0 + a_row) < M;

    const int b0_row = tid >> 2, b0_slot = tid & 3;
    const int b1_row = 64 + (tid >> 2);
    const bool has_b1 = (tid < 128);

    short8 areg, breg0, breg1;

    auto LOAD = [&](int kt) {
        const int kb = kt * 32;
        areg = (short8){0,0,0,0,0,0,0,0};
        if (avalid)
            areg = *reinterpret_cast<const short8*>(A + (size_t)(m0 + a_row) * K + kb + a_slot * 8);
        breg0 = *reinterpret_cast<const short8*>(Bt + (size_t)(n0 + b0_row) * K + kb + b0_slot * 8);
        if (has_b1)
            breg1 = *reinterpret_cast<const short8*>(Bt + (size_t)(n0 + b1_row) * K + kb + b0_slot * 8);
    };

    auto STAGE = [&](int buf) {
        *reinterpret_cast<short8*>(&As[buf][swz(a_row, a_slot)]) = areg;
        *reinterpret_cast<short8*>(&Bs[buf][swz(b0_row, b0_slot)]) = breg0;
        if (has_b1)
            *reinterpret_cast<short8*>(&Bs[buf][swz(b1_row, b0_slot)]) = breg1;
    };

    f32x4 acc[2][3];
#pragma unroll
    for (int m = 0; m < 2; ++m)
#pragma unroll
        for (int n = 0; n < 3; ++n) acc[m][n] = (f32x4){0.f, 0.f, 0.f, 0.f};

    const int nsteps = K / 32;
    LOAD(0);
    STAGE(0);
    LOAD(1);
    __syncthreads();

    const int kgrp = lane >> 4;
    const int lr   = lane & 15;

    for (int kt = 0; kt < nsteps; ++kt) {
        const int cur = kt & 1;
        short8 afrag[2], bfrag[3];
#pragma unroll
        for (int m = 0; m < 2; ++m) {
            int r = wm * 32 + m * 16 + lr;
            afrag[m] = *reinterpret_cast<const short8*>(&As[cur][swz(r, kgrp)]);
        }
#pragma unroll
        for (int n = 0; n < 3; ++n) {
            int c = wn * 48 + n * 16 + lr;
            bfrag[n] = *reinterpret_cast<const short8*>(&Bs[cur][swz(c, kgrp)]);
        }
        if (kt + 1 < nsteps) {
            STAGE(cur ^ 1);
            if (kt + 2 < nsteps) LOAD(kt + 2);
        }
#pragma unroll
        for (int m = 0; m < 2; ++m)
#pragma unroll
            for (int n = 0; n < 3; ++n)
                acc[m][n] = __builtin_amdgcn_mfma_f32_16x16x32_bf16(
                    afrag[m], bfrag[n], acc[m][n], 0, 0, 0);
        if (kt + 1 < nsteps) __syncthreads();
    }

    const int rq = lane >> 4;
#pragma unroll
    for (int m = 0; m < 2; ++m) {
        int rbase = m0 + wm * 32 + m * 16 + rq * 4;
#pragma unroll
        for (int n = 0; n < 3; ++n) {
            int col = n0 + wn * 48 + n * 16 + lr;
#pragma unroll
            for (int r = 0; r < 4; ++r) {
                int row = rbase + r;
                if (row < M)
                    Cout[(size_t)row * N + col] =
                        acc[m][n][r] + Cin[(size_t)row * N + col];
            }
        }
    }
}

}  // namespace

extern "C" void kernel_launch(void* const* d_in, const int* in_sizes, int n_in,
                              void* d_out, int out_size, void* d_ws, size_t ws_size,
                              hipStream_t stream) {
    const float* hs     = (const float*)d_in[0];
    const int*   coords = (const int*)d_in[1];
    const float* w_down = (const float*)d_in[2];
    const float* w3     = (const float*)d_in[3];
    const float* w2     = (const float*)d_in[4];
    const float* w_up   = (const float*)d_in[5];
    float* out = (float*)d_out;

    int* cnt_i   = (int*)d_ws;                          // NVOX int
    int* vox_pts = cnt_i + NVOX;                        // NVOX*MAXP int
    unsigned short* xbuf  = (unsigned short*)(vox_pts + (size_t)NVOX * MAXP); // NPTS*CD
    unsigned short* ptf   = xbuf + (size_t)NPTS * CD;   // NPTS*CD bf16
    unsigned short* smbuf = ptf + (size_t)NPTS * CD;    // NPTS*CD bf16
    unsigned short* wdt   = smbuf + (size_t)NPTS * CD;  // [CD][C] bf16
    unsigned short* wut   = wdt + (size_t)CD * C;       // [C][CD] bf16
    float* w3t = (float*)(wut + (size_t)C * CD);        // [27][288] f32

    // 1. prep: weight transposes + zero cnt_i + w3 transpose
    k_combo<<<dim3(NB_ALL), dim3(256), 0, stream>>>(
        w_down, w_up, w3, wdt, wut, w3t, cnt_i);

    // 2. GEMM1: dense bf16 x + voxel point-list build (3-deep A prefetch)
    k_gemm1<<<dim3(CD / 96, (NPTS + 31) / 32), dim3(256), 0, stream>>>(
        hs, wdt, coords, cnt_i, vox_pts, xbuf);

    // 3. depthwise conv3d (vectorized, 7 pts/block, entry lists) + gelu
    k_conv3<<<dim3((NPTS + C3_PTS - 1) / C3_PTS), dim3(256), 0, stream>>>(
        coords, xbuf, cnt_i, vox_pts, w3t, ptf);

    // 4. depthwise conv2d (vectorized, 7 pts/block)
    k_conv2<<<dim3((NPTS + C2_PTS - 1) / C2_PTS), dim3(256), 0, stream>>>(
        ptf, w2, smbuf);

    // 5. out = hs + sm @ w_up
    k_gemm2<<<dim3(C / 96, (NPTS + 63) / 64), dim3(256), 0, stream>>>(
        smbuf, wut, hs, out, NPTS, C, CD);
}